// Round 16
// baseline (188.325 us; speedup 1.0000x reference)
//
#include <hip/hip_runtime.h>

// Problem constants
#define BB    128
#define CC    272
#define CPAD  288     // K padded to 9*32 (rows 272..287 zeroed in LDS)
#define TT    512
#define DD1   320
#define NT    32      // t-tile per block (halved: 8 blocks/CU LDS-capped)
#define MT    160     // d-tile per block (D1 split in 2)
#define LDC2  34      // Xs row stride, bf16 (68 B): quad spans 4 disjoint 8-bank groups, 2 lanes/bank = free

typedef float  f32x4  __attribute__((ext_vector_type(4)));
typedef __bf16 bf16x4 __attribute__((ext_vector_type(4)));
typedef __bf16 bf16x8 __attribute__((ext_vector_type(8)));

// lgkm-only barrier: orders LDS ops without draining vmcnt (global af-prefetch
// issued before it stays in flight).
#define BAR() asm volatile("s_waitcnt lgkmcnt(0)\ns_barrier" ::: "memory")

// ---- prepass: W f32 -> bf16 into workspace
__global__ __launch_bounds__(256)
void w_cvt(const float* __restrict__ W, __bf16* __restrict__ Wb) {
    const int i = blockIdx.x * 256 + threadIdx.x;      // 87040 threads
    const float4* src = (const float4*)W;
    const float4 a = src[2 * i];
    const float4 b = src[2 * i + 1];
    bf16x8 h = {(__bf16)a.x, (__bf16)a.y, (__bf16)a.z, (__bf16)a.w,
                (__bf16)b.x, (__bf16)b.y, (__bf16)b.z, (__bf16)b.w};
    *(bf16x8*)(Wb + 8 * i) = h;
}

// out[b,d,t] = sum_c W[s_b,d,c] * X[b,c,t]
// Grid (B, T/32, 2) = 4096 blocks, 256 thr / 4 waves as 2(m) x 2(n), nt=1.
// NT=32 TLP experiment: every 66us variant ran at <=4 blocks/CU (26-35%
// occupancy); R6 (57% occ) is the only run that pulled 3.77 TB/s. Xs at
// 19.6 KB doubles nominal residency to 6-8 blocks/CU (24-32 waves) so
// block phases (stage burst / af-chain / store burst) overlap across 2x
// more independent blocks. Barrier-free K-loop (R9), af depth-2 from bf16
// workspace, 0-conflict LDS layout, verified fragment/epilogue maps.
// Staging: all 9 float4 loads issued before any LDS write (max wave MLP).
template <bool WB16>
__global__ __launch_bounds__(256, 4)
void subj_conv_tlp(const float*  __restrict__ X,
                   const int*    __restrict__ sidx,
                   const float*  __restrict__ W,
                   const __bf16* __restrict__ Wbf,
                   float*        __restrict__ out) {
    const int b  = blockIdx.x;
    const int T0 = blockIdx.y * NT;
    const int d0 = blockIdx.z * MT;
    const int s  = sidx[b];

    __shared__ __align__(16) __bf16 Xs[CPAD * LDC2];   // 19,584 B

    const int tid  = threadIdx.x;
    const int lane = tid & 63;
    const int wv   = tid >> 6;
    const int wm   = wv & 1;          // m-half (80 rows)
    const int wn   = wv >> 1;         // n-half (16 t)
    const int quad = lane >> 4;
    const int l16  = lane & 15;

    // ---- stage full-K X tile: 288 c x 32 t. 9 passes x (32 c-rows x 32 t).
    // All 9 loads in flight before the first LDS write (counted vmcnt waits).
    {
        const float* Xb = X + (size_t)b * CC * TT + T0;
        const int xr = tid >> 3;              // 0..31
        const int xt = (tid & 7) * 4;         // 0..28
        float4 v[9];
#pragma unroll
        for (int p = 0; p < 9; ++p) {
            const int c = xr + 32 * p;
            v[p] = make_float4(0.f, 0.f, 0.f, 0.f);
            if (c < CC) v[p] = *(const float4*)(Xb + (size_t)c * TT + xt);
        }
#pragma unroll
        for (int p = 0; p < 9; ++p) {
            const int c = xr + 32 * p;
            bf16x4 h = {(__bf16)v[p].x, (__bf16)v[p].y,
                        (__bf16)v[p].z, (__bf16)v[p].w};
            *(bf16x4*)&Xs[c * LDC2 + xt] = h;
        }
    }

    // per-lane W fragment base: d-row = d0+wm*80+mt*16+l16, k-octet = quad*8
    const size_t wrow = ((size_t)s * DD1 + d0 + wm * 80 + l16) * CC + quad * 8;
    const __bf16* Wp16 = Wbf + (WB16 ? wrow : 0);
    const float*  Wp32 = W   + (WB16 ? 0 : wrow);

    auto load_af = [&](int mt, int kc) -> bf16x8 {   // caller guarantees liveness
        const int off = mt * 16 * CC + kc * 32;
        if constexpr (WB16) {
            return *(const bf16x8*)(Wp16 + off);
        } else {
            const float4 u0 = *(const float4*)(Wp32 + off);
            const float4 u1 = *(const float4*)(Wp32 + off + 4);
            return bf16x8{(__bf16)u0.x, (__bf16)u0.y, (__bf16)u0.z, (__bf16)u0.w,
                          (__bf16)u1.x, (__bf16)u1.y, (__bf16)u1.z, (__bf16)u1.w};
        }
    };

    bf16x8 af[2][5];          // two named sets; all indices compile-time (full unroll)
    bf16x8 bfr[2];

    // prologue: af for kc=0,1 issued BEFORE the barrier (lgkm-only -> stay in flight)
#pragma unroll
    for (int mt = 0; mt < 5; ++mt) af[0][mt] = load_af(mt, 0);
#pragma unroll
    for (int mt = 0; mt < 5; ++mt) af[1][mt] = load_af(mt, 1);
    BAR();

    const int tc = wn * 16 + l16;         // this wave's t column
    // b frag for kc=0
#pragma unroll
    for (int j = 0; j < 8; ++j)
        bfr[0][j] = Xs[(quad * 8 + j) * LDC2 + tc];

    f32x4 acc[5];
#pragma unroll
    for (int mt = 0; mt < 5; ++mt)
        acc[mt] = (f32x4){0.f, 0.f, 0.f, 0.f};

#pragma unroll
    for (int kc = 0; kc < 9; ++kc) {
        const int cur = kc & 1;
        const int nx  = cur ^ 1;
        // depth-1 LDS prefetch: b frag for kc+1 (consumed next body)
        if (kc + 1 < 9) {
#pragma unroll
            for (int j = 0; j < 8; ++j)
                bfr[nx][j] = Xs[((kc + 1) * 32 + quad * 8 + j) * LDC2 + tc];
        }
#pragma unroll
        for (int mt = 0; mt < 5; ++mt) {
            acc[mt] = __builtin_amdgcn_mfma_f32_16x16x32_bf16(af[cur][mt], bfr[cur],
                                                              acc[mt], 0, 0, 0);
            // refill the consumed slot with kc+2 (depth-2, ~2 bodies of slack)
            if (kc + 2 < 8) {
                af[cur][mt] = load_af(mt, kc + 2);
            } else if (kc + 2 == 8) {
                bf16x8 a = {(__bf16)0.f, (__bf16)0.f, (__bf16)0.f, (__bf16)0.f,
                            (__bf16)0.f, (__bf16)0.f, (__bf16)0.f, (__bf16)0.f};
                if (quad < 2) a = load_af(mt, 8);   // k 256..287: only quads 0,1 in-bounds
                af[cur][mt] = a;
            }
        }
    }

    // ---- epilogue (verified map): D[m = quad*4 + r][n = l16]
#pragma unroll
    for (int mt = 0; mt < 5; ++mt) {
        const int d = d0 + wm * 80 + mt * 16 + quad * 4;
        float* ob = out + ((size_t)b * DD1 + d) * TT + T0 + tc;
#pragma unroll
        for (int r = 0; r < 4; ++r)
            ob[(size_t)r * TT] = acc[mt][r];
    }
}

extern "C" void kernel_launch(void* const* d_in, const int* in_sizes, int n_in,
                              void* d_out, int out_size, void* d_ws, size_t ws_size,
                              hipStream_t stream) {
    const float* X    = (const float*)d_in[0];   // [B, C, T]
    const int*   sidx = (const int*)  d_in[1];   // [B]
    const float* W    = (const float*)d_in[2];   // [S, D1, C]
    float*       out  = (float*)d_out;           // [B, D1, T]

    dim3 grid(BB, TT / NT, 2);   // 128 x 16 x 2 = 4096 blocks
    dim3 block(256);

    const size_t need = (size_t)8 * DD1 * CC * sizeof(__bf16);   // 1,392,640 B
    if (d_ws && ws_size >= need) {
        __bf16* Wb = (__bf16*)d_ws;
        w_cvt<<<dim3(340), dim3(256), 0, stream>>>(W, Wb);
        subj_conv_tlp<true><<<grid, block, 0, stream>>>(X, sidx, W, Wb, out);
    } else {
        subj_conv_tlp<false><<<grid, block, 0, stream>>>(X, sidx, W, nullptr, out);
    }
}

// Round 17
// 163.966 us; speedup vs baseline: 1.1486x; 1.1486x over previous
//
#include <hip/hip_runtime.h>

// Problem constants
#define BB    128
#define CC    272
#define CPAD  288     // K padded to 9*32 (rows 272..287 zeroed in LDS)
#define TT    512
#define DD1   320
#define NT    128     // t-tile per block (nt=4 per wave: each af feeds 4 MFMAs)
#define MT    160     // d-tile per block (D1 split in 2)
#define LDC   130     // Xs row stride, bf16 (260 B): bank = (c*65 + t/2)%32 -> conflict-free

typedef float  f32x4  __attribute__((ext_vector_type(4)));
typedef __bf16 bf16x4 __attribute__((ext_vector_type(4)));
typedef __bf16 bf16x8 __attribute__((ext_vector_type(8)));

// lgkm-only barrier: orders LDS ops without draining vmcnt.
#define BAR() asm volatile("s_waitcnt lgkmcnt(0)\ns_barrier" ::: "memory")

// ---- prepass: W f32 -> bf16 into workspace
__global__ __launch_bounds__(256)
void w_cvt(const float* __restrict__ W, __bf16* __restrict__ Wb) {
    const int i = blockIdx.x * 256 + threadIdx.x;      // 87040 threads
    const float4* src = (const float4*)W;
    const float4 a = src[2 * i];
    const float4 b = src[2 * i + 1];
    bf16x8 h = {(__bf16)a.x, (__bf16)a.y, (__bf16)a.z, (__bf16)a.w,
                (__bf16)b.x, (__bf16)b.y, (__bf16)b.z, (__bf16)b.w};
    *(bf16x8*)(Wb + 8 * i) = h;
}

// out[b,d,t] = sum_c W[s_b,d,c] * X[b,c,t]
// Grid (B, T/128, 2) = 1024 blocks, 256 thr / 4 waves as 2(m) x 2(n), nt=4.
// CHAIN-TOTAL optimization: the surviving model across 17 runs is per-wave
// serial load->use chains (compiler sinks af loads; VGPR 48-68 everywhere),
// ~4-way SIMD interleave. So minimize TOTAL chain work: nt=4 means each af
// load feeds 4 MFMAs -> af instructions halve (368k -> 184k), waves halve
// (8192 -> 4096), staging+store+MFMA totals invariant. R16 did the inverse
// (nt=1: af x2, waves x2) and regressed 66 -> 87 exactly as the model says.
// Xs = 74.9 KB (gfx950 allows 160 KB/workgroup) -> 2 blocks/CU.
template <bool WB16>
__global__ __launch_bounds__(256, 2)
void subj_conv_fat(const float*  __restrict__ X,
                   const int*    __restrict__ sidx,
                   const float*  __restrict__ W,
                   const __bf16* __restrict__ Wbf,
                   float*        __restrict__ out) {
    const int b  = blockIdx.x;
    const int T0 = blockIdx.y * NT;
    const int d0 = blockIdx.z * MT;
    const int s  = sidx[b];

    __shared__ __align__(16) __bf16 Xs[CPAD * LDC];   // 74,880 B

    const int tid  = threadIdx.x;
    const int lane = tid & 63;
    const int wv   = tid >> 6;
    const int wm   = wv & 1;          // m-half (80 rows)
    const int wn   = wv >> 1;         // n-half (64 t)
    const int quad = lane >> 4;
    const int l16  = lane & 15;

    // ---- stage full-K X tile: 288 c x 128 t; 36 passes of 8 rows, batch 6.
    {
        const float* Xb = X + (size_t)b * CC * TT + T0;
        const int xr = tid >> 5;              // 0..7
        const int xt = (tid & 31) * 4;        // 0..124
#pragma unroll
        for (int pb = 0; pb < 6; ++pb) {
            float4 v[6];
#pragma unroll
            for (int q = 0; q < 6; ++q) {
                const int c = xr + 8 * (pb * 6 + q);
                v[q] = make_float4(0.f, 0.f, 0.f, 0.f);
                if (c < CC) v[q] = *(const float4*)(Xb + (size_t)c * TT + xt);
            }
#pragma unroll
            for (int q = 0; q < 6; ++q) {
                const int c = xr + 8 * (pb * 6 + q);
                bf16x4 h = {(__bf16)v[q].x, (__bf16)v[q].y,
                            (__bf16)v[q].z, (__bf16)v[q].w};
                *(bf16x4*)&Xs[c * LDC + xt] = h;
            }
        }
    }

    // per-lane W fragment base: d-row = d0+wm*80+mt*16+l16, k-octet = quad*8
    const size_t wrow = ((size_t)s * DD1 + d0 + wm * 80 + l16) * CC + quad * 8;
    const __bf16* Wp16 = Wbf + (WB16 ? wrow : 0);
    const float*  Wp32 = W   + (WB16 ? 0 : wrow);

    auto load_af = [&](int mt, int kc) -> bf16x8 {   // caller guarantees liveness
        const int off = mt * 16 * CC + kc * 32;
        if constexpr (WB16) {
            return *(const bf16x8*)(Wp16 + off);
        } else {
            const float4 u0 = *(const float4*)(Wp32 + off);
            const float4 u1 = *(const float4*)(Wp32 + off + 4);
            return bf16x8{(__bf16)u0.x, (__bf16)u0.y, (__bf16)u0.z, (__bf16)u0.w,
                          (__bf16)u1.x, (__bf16)u1.y, (__bf16)u1.z, (__bf16)u1.w};
        }
    };

    bf16x8 af[2][5];          // two named sets; all indices compile-time (full unroll)
    bf16x8 bfr[2][4];

    // prologue: af for kc=0,1 issued BEFORE the barrier (lgkm-only -> stay in flight)
#pragma unroll
    for (int mt = 0; mt < 5; ++mt) af[0][mt] = load_af(mt, 0);
#pragma unroll
    for (int mt = 0; mt < 5; ++mt) af[1][mt] = load_af(mt, 1);
    BAR();

    const int tcb = wn * 64 + l16;        // base t column; frags at tcb + nt*16
    // b frags for kc=0
#pragma unroll
    for (int nt = 0; nt < 4; ++nt)
#pragma unroll
        for (int j = 0; j < 8; ++j)
            bfr[0][nt][j] = Xs[(quad * 8 + j) * LDC + tcb + nt * 16];

    f32x4 acc[5][4];
#pragma unroll
    for (int mt = 0; mt < 5; ++mt)
#pragma unroll
        for (int nt = 0; nt < 4; ++nt)
            acc[mt][nt] = (f32x4){0.f, 0.f, 0.f, 0.f};

#pragma unroll
    for (int kc = 0; kc < 9; ++kc) {
        const int cur = kc & 1;
        const int nx  = cur ^ 1;
        // depth-1 LDS prefetch: b frags for kc+1 (consumed next body)
        if (kc + 1 < 9) {
#pragma unroll
            for (int nt = 0; nt < 4; ++nt)
#pragma unroll
                for (int j = 0; j < 8; ++j)
                    bfr[nx][nt][j] = Xs[((kc + 1) * 32 + quad * 8 + j) * LDC + tcb + nt * 16];
        }
#pragma unroll
        for (int mt = 0; mt < 5; ++mt) {
            // consume af[cur][mt] across 4 n-fragments ...
#pragma unroll
            for (int nt = 0; nt < 4; ++nt)
                acc[mt][nt] = __builtin_amdgcn_mfma_f32_16x16x32_bf16(
                    af[cur][mt], bfr[cur][nt], acc[mt][nt], 0, 0, 0);
            // ... then refill the slot with kc+2 (depth-2 intent; harmless if sunk)
            if (kc + 2 < 8) {
                af[cur][mt] = load_af(mt, kc + 2);
            } else if (kc + 2 == 8) {
                bf16x8 a = {(__bf16)0.f, (__bf16)0.f, (__bf16)0.f, (__bf16)0.f,
                            (__bf16)0.f, (__bf16)0.f, (__bf16)0.f, (__bf16)0.f};
                if (quad < 2) a = load_af(mt, 8);   // k 256..287: only quads 0,1 in-bounds
                af[cur][mt] = a;
            }
        }
    }

    // ---- epilogue (verified map): D[m = quad*4 + r][n = l16]
#pragma unroll
    for (int mt = 0; mt < 5; ++mt) {
        const int d = d0 + wm * 80 + mt * 16 + quad * 4;
#pragma unroll
        for (int nt = 0; nt < 4; ++nt) {
            float* ob = out + ((size_t)b * DD1 + d) * TT + T0 + wn * 64 + nt * 16 + l16;
#pragma unroll
            for (int r = 0; r < 4; ++r)
                ob[(size_t)r * TT] = acc[mt][nt][r];
        }
    }
}

extern "C" void kernel_launch(void* const* d_in, const int* in_sizes, int n_in,
                              void* d_out, int out_size, void* d_ws, size_t ws_size,
                              hipStream_t stream) {
    const float* X    = (const float*)d_in[0];   // [B, C, T]
    const int*   sidx = (const int*)  d_in[1];   // [B]
    const float* W    = (const float*)d_in[2];   // [S, D1, C]
    float*       out  = (float*)d_out;           // [B, D1, T]

    dim3 grid(BB, TT / NT, 2);   // 128 x 4 x 2 = 1024 blocks
    dim3 block(256);

    const size_t need = (size_t)8 * DD1 * CC * sizeof(__bf16);   // 1,392,640 B
    if (d_ws && ws_size >= need) {
        __bf16* Wb = (__bf16*)d_ws;
        w_cvt<<<dim3(340), dim3(256), 0, stream>>>(W, Wb);
        subj_conv_fat<true><<<grid, block, 0, stream>>>(X, sidx, W, Wb, out);
    } else {
        subj_conv_fat<false><<<grid, block, 0, stream>>>(X, sidx, W, nullptr, out);
    }
}

// Round 19
// 155.990 us; speedup vs baseline: 1.2073x; 1.0511x over previous
//
#include <hip/hip_runtime.h>

// Problem constants
#define BB    128
#define CC    272
#define CPAD  288     // K padded to 9*32 (rows 272..287 zeroed in LDS)
#define TT    512
#define DD1   320
#define NT    128     // t-tile per block (nt=4 per wave: each af feeds 4 MFMAs)
#define MT    160     // d-tile per block (D1 split in 2, z-paired on one XCD)
#define LDC   130     // Xs row stride, bf16 (260 B): bank = (c*65 + t/2)%32 -> conflict-free

typedef float  f32x4  __attribute__((ext_vector_type(4)));
typedef __bf16 bf16x4 __attribute__((ext_vector_type(4)));
typedef __bf16 bf16x8 __attribute__((ext_vector_type(8)));

// lgkm-only barrier: orders LDS ops without draining vmcnt.
#define BAR() asm volatile("s_waitcnt lgkmcnt(0)\ns_barrier" ::: "memory")

// ---- prepass: W f32 -> bf16 into workspace
__global__ __launch_bounds__(256)
void w_cvt(const float* __restrict__ W, __bf16* __restrict__ Wb) {
    const int i = blockIdx.x * 256 + threadIdx.x;      // 87040 threads
    const float4* src = (const float4*)W;
    const float4 a = src[2 * i];
    const float4 b = src[2 * i + 1];
    bf16x8 h = {(__bf16)a.x, (__bf16)a.y, (__bf16)a.z, (__bf16)a.w,
                (__bf16)b.x, (__bf16)b.y, (__bf16)b.z, (__bf16)b.w};
    *(bf16x8*)(Wb + 8 * i) = h;
}

// out[b,d,t] = sum_c W[s_b,d,c] * X[b,c,t]
// 1024 blocks (1D), 256 thr / 4 waves as 2(m) x 2(n), nt=4 (R17 winner, 62us).
// + XCD-chunked, z-INNERMOST decode: orig = (bid%8)*128 + bid/8;
//   b = orig>>3, ty = (orig&7)>>1, z = orig&1. Bijective (1024%8==0).
//   The two d-halves of one (b,T0) are adjacent ids on the SAME XCD, and all
//   8 tiles of one b are consecutive there -> first stager warms X[b] into
//   that XCD's L2 (0.56MB << 4MB); siblings stage at ~200-300cy not ~900.
// + staging batch 12 (was 6): cold-stage = 3 latency waits instead of 6.
// Chain model (survived 17 rounds): time ~ total serial load-latency work /
// resident contexts. This round shortens the staging chains at constant
// context count; R17 shortened af chains (66->62).
template <bool WB16>
__global__ __launch_bounds__(256, 2)
void subj_conv_fat(const float*  __restrict__ X,
                   const int*    __restrict__ sidx,
                   const float*  __restrict__ W,
                   const __bf16* __restrict__ Wbf,
                   float*        __restrict__ out) {
    const int bid  = blockIdx.x;                 // 0..1023
    const int orig = (bid & 7) * 128 + (bid >> 3);
    const int b    = orig >> 3;
    const int T0   = ((orig & 7) >> 1) * NT;
    const int d0   = (orig & 1) * MT;
    const int s    = sidx[b];

    __shared__ __align__(16) __bf16 Xs[CPAD * LDC];   // 74,880 B

    const int tid  = threadIdx.x;
    const int lane = tid & 63;
    const int wv   = tid >> 6;
    const int wm   = wv & 1;          // m-half (80 rows)
    const int wn   = wv >> 1;         // n-half (64 t)
    const int quad = lane >> 4;
    const int l16  = lane & 15;

    // ---- stage full-K X tile: 288 c x 128 t; 36 passes of 8 rows, batch 12.
    {
        const float* Xb = X + (size_t)b * CC * TT + T0;
        const int xr = tid >> 5;              // 0..7
        const int xt = (tid & 31) * 4;        // 0..124
#pragma unroll
        for (int g = 0; g < 3; ++g) {
            float4 v[12];
#pragma unroll
            for (int q = 0; q < 12; ++q) {
                const int c = xr + 8 * (g * 12 + q);
                v[q] = make_float4(0.f, 0.f, 0.f, 0.f);
                if (c < CC) v[q] = *(const float4*)(Xb + (size_t)c * TT + xt);
            }
#pragma unroll
            for (int q = 0; q < 12; ++q) {
                const int c = xr + 8 * (g * 12 + q);
                bf16x4 h = {(__bf16)v[q].x, (__bf16)v[q].y,
                            (__bf16)v[q].z, (__bf16)v[q].w};
                *(bf16x4*)&Xs[c * LDC + xt] = h;
            }
        }
    }

    // per-lane W fragment base: d-row = d0+wm*80+mt*16+l16, k-octet = quad*8
    const size_t wrow = ((size_t)s * DD1 + d0 + wm * 80 + l16) * CC + quad * 8;
    const __bf16* Wp16 = Wbf + (WB16 ? wrow : 0);
    const float*  Wp32 = W   + (WB16 ? 0 : wrow);

    auto load_af = [&](int mt, int kc) -> bf16x8 {   // caller guarantees liveness
        const int off = mt * 16 * CC + kc * 32;
        if constexpr (WB16) {
            return *(const bf16x8*)(Wp16 + off);
        } else {
            const float4 u0 = *(const float4*)(Wp32 + off);
            const float4 u1 = *(const float4*)(Wp32 + off + 4);
            return bf16x8{(__bf16)u0.x, (__bf16)u0.y, (__bf16)u0.z, (__bf16)u0.w,
                          (__bf16)u1.x, (__bf16)u1.y, (__bf16)u1.z, (__bf16)u1.w};
        }
    };

    bf16x8 af[2][5];          // two named sets; all indices compile-time (full unroll)
    bf16x8 bfr[2][4];

    // prologue: af for kc=0,1 issued BEFORE the barrier (lgkm-only -> stay in flight)
#pragma unroll
    for (int mt = 0; mt < 5; ++mt) af[0][mt] = load_af(mt, 0);
#pragma unroll
    for (int mt = 0; mt < 5; ++mt) af[1][mt] = load_af(mt, 1);
    BAR();

    const int tcb = wn * 64 + l16;        // base t column; frags at tcb + nt*16
    // b frags for kc=0
#pragma unroll
    for (int nt = 0; nt < 4; ++nt)
#pragma unroll
        for (int j = 0; j < 8; ++j)
            bfr[0][nt][j] = Xs[(quad * 8 + j) * LDC + tcb + nt * 16];

    f32x4 acc[5][4];
#pragma unroll
    for (int mt = 0; mt < 5; ++mt)
#pragma unroll
        for (int nt = 0; nt < 4; ++nt)
            acc[mt][nt] = (f32x4){0.f, 0.f, 0.f, 0.f};

#pragma unroll
    for (int kc = 0; kc < 9; ++kc) {
        const int cur = kc & 1;
        const int nx  = cur ^ 1;
        // depth-1 LDS prefetch: b frags for kc+1 (consumed next body)
        if (kc + 1 < 9) {
#pragma unroll
            for (int nt = 0; nt < 4; ++nt)
#pragma unroll
                for (int j = 0; j < 8; ++j)
                    bfr[nx][nt][j] = Xs[((kc + 1) * 32 + quad * 8 + j) * LDC + tcb + nt * 16];
        }
#pragma unroll
        for (int mt = 0; mt < 5; ++mt) {
            // consume af[cur][mt] across 4 n-fragments ...
#pragma unroll
            for (int nt = 0; nt < 4; ++nt)
                acc[mt][nt] = __builtin_amdgcn_mfma_f32_16x16x32_bf16(
                    af[cur][mt], bfr[cur][nt], acc[mt][nt], 0, 0, 0);
            // ... then refill the slot with kc+2 (depth-2; VGPR=104 shows it lives)
            if (kc + 2 < 8) {
                af[cur][mt] = load_af(mt, kc + 2);
            } else if (kc + 2 == 8) {
                bf16x8 a = {(__bf16)0.f, (__bf16)0.f, (__bf16)0.f, (__bf16)0.f,
                            (__bf16)0.f, (__bf16)0.f, (__bf16)0.f, (__bf16)0.f};
                if (quad < 2) a = load_af(mt, 8);   // k 256..287: only quads 0,1 in-bounds
                af[cur][mt] = a;
            }
        }
    }

    // ---- epilogue (verified map): D[m = quad*4 + r][n = l16]
#pragma unroll
    for (int mt = 0; mt < 5; ++mt) {
        const int d = d0 + wm * 80 + mt * 16 + quad * 4;
#pragma unroll
        for (int nt = 0; nt < 4; ++nt) {
            float* ob = out + ((size_t)b * DD1 + d) * TT + T0 + wn * 64 + nt * 16 + l16;
#pragma unroll
            for (int r = 0; r < 4; ++r)
                ob[(size_t)r * TT] = acc[mt][nt][r];
        }
    }
}

extern "C" void kernel_launch(void* const* d_in, const int* in_sizes, int n_in,
                              void* d_out, int out_size, void* d_ws, size_t ws_size,
                              hipStream_t stream) {
    const float* X    = (const float*)d_in[0];   // [B, C, T]
    const int*   sidx = (const int*)  d_in[1];   // [B]
    const float* W    = (const float*)d_in[2];   // [S, D1, C]
    float*       out  = (float*)d_out;           // [B, D1, T]

    dim3 grid(BB * (TT / NT) * 2);   // 1024 blocks, XCD-chunked z-inner decode
    dim3 block(256);

    const size_t need = (size_t)8 * DD1 * CC * sizeof(__bf16);   // 1,392,640 B
    if (d_ws && ws_size >= need) {
        __bf16* Wb = (__bf16*)d_ws;
        w_cvt<<<dim3(340), dim3(256), 0, stream>>>(W, Wb);
        subj_conv_fat<true><<<grid, block, 0, stream>>>(X, sidx, W, Wb, out);
    } else {
        subj_conv_fat<false><<<grid, block, 0, stream>>>(X, sidx, W, nullptr, out);
    }
}